// Round 3
// baseline (102.177 us; speedup 1.0000x reference)
//
#include <hip/hip_runtime.h>
#include <math.h>

// VQ quantizer: x [512,256,12] fp32, codebook [512,12] fp32.
// Outputs (concat fp32): quantized_st [512*256*12], indices-as-float [512*256], loss [1].
//
// R10: R9 aimed for the <=64-VGPR tier via compiler-promoted scalar loads of
// the wave-uniform codebook rows; total only moved 94.5->88.8 and the math
// says vq_main stayed ~39us => promotion (or the tier) didn't materialize.
// This round FORCES it: inline-asm s_load_dwordx16 pulls each packed 64B row
// [w0..w11, w2, pad3] straight into SGPRs (1 SMEM instr/code), double-buffered,
// with each s_waitcnt carrying the row tuple as a "+s" in-out operand so FMA
// consumers are DATAFLOW-ordered after the wait (rule-18-safe; each wait has
// exactly one outstanding SMEM op => out-of-order SMEM return is harmless).
// VGPR budget: xs 24 + best/bi/x2 6 + temps ~12 => ~45 < 64 => 8 waves/SIMD,
// 1024 blocks x 512 thr = 4 blocks/CU = 32 waves/CU (full).
// launch_bounds(512,4) remains a CAP, never a spill-forcing demand (R8 lesson).
namespace {
constexpr int KCB   = 512;
constexpr int DIM   = 12;
constexpr int NTOK  = 512 * 256;       // 131072
constexpr int QSIZE = NTOK * DIM;      // 1572864
constexpr int NSPLIT = 8;              // waves per block == K chunks
constexpr int KCHUNK = KCB / NSPLIT;   // 64 codes per wave
constexpr int TPT    = 2;              // tokens/thread
constexpr int TOKS_PER_BLOCK = 64 * TPT;        // 128
constexpr int NBLK   = NTOK / TOKS_PER_BLOCK;   // 1024 blocks x 512 thr
constexpr int ROWF   = 16;             // packed row: w[12], w2, pad[3] (64 B)
// ws layout: pk[513][16] floats (row 512 = zero pad for the tail prefetch)

typedef __attribute__((ext_vector_type(16))) float f32x16;

// EXACT score sequence validated R1-R9 (absmax 0.0 vs numpy). Do not reorder.
// Row elements come from SGPRs: v_fma_f32 vdst, v(xv), s(w), v(acc) — exactly
// one scalar operand per VALU instr, which gfx950 allows.
__device__ inline float code_score_s(const float (&xv)[DIM], float x2,
                                     const f32x16& r) {
    float xw = 0.f;
    xw = fmaf(xv[0],  r[0],  xw);
    xw = fmaf(xv[1],  r[1],  xw);
    xw = fmaf(xv[2],  r[2],  xw);
    xw = fmaf(xv[3],  r[3],  xw);
    xw = fmaf(xv[4],  r[4],  xw);
    xw = fmaf(xv[5],  r[5],  xw);
    xw = fmaf(xv[6],  r[6],  xw);
    xw = fmaf(xv[7],  r[7],  xw);
    xw = fmaf(xv[8],  r[8],  xw);
    xw = fmaf(xv[9],  r[9],  xw);
    xw = fmaf(xv[10], r[10], xw);
    xw = fmaf(xv[11], r[11], xw);
    return fmaf(-2.f, xw, x2) + r[12];
}

// u64 (monotone(score), k) unsigned-min == exact lexicographic
// first-occurrence argmin (validated R2-R9).
__device__ inline unsigned long long mkkey(float v, int k) {
    unsigned su = __float_as_uint(v);
    su = (su & 0x80000000u) ? ~su : (su | 0x80000000u);
    return ((unsigned long long)su << 32) | (unsigned)k;
}

// Pack codebook into 64 B rows [w0..w11, w2, 0,0,0] (w2 = exact fmaf chain,
// same rounding as R1-R9). Also zeroes the loss accumulator (this dispatch
// precedes vq_main in-stream => ordered before the atomics, and re-runs on
// every replay after harness re-poisoning).
__global__ __launch_bounds__(256) void pack_cb(const float* __restrict__ cb,
                                               float* __restrict__ pk,
                                               float* __restrict__ out) {
    int k = blockIdx.x * blockDim.x + threadIdx.x;
    if (k == 0) out[QSIZE + NTOK] = 0.f;
    if (k >= KCB) return;
    float w[DIM];
#pragma unroll
    for (int d = 0; d < DIM; ++d) w[d] = cb[k * DIM + d];
    float w2 = 0.f;
#pragma unroll
    for (int d = 0; d < DIM; ++d) w2 = fmaf(w[d], w[d], w2);
#pragma unroll
    for (int d = 0; d < DIM; ++d) pk[k * ROWF + d] = w[d];
    pk[k * ROWF + 12] = w2;
    pk[k * ROWF + 13] = 0.f; pk[k * ROWF + 14] = 0.f; pk[k * ROWF + 15] = 0.f;
    if (k == KCB - 1) {  // zero pad row 512 (read by tail prefetch, never scored)
#pragma unroll
        for (int d = 0; d < ROWF; ++d) pk[KCB * ROWF + d] = 0.f;
    }
}

// Block = 128 tokens x 8 K-splits. Codebook rows live in SGPRs via forced
// s_load_dwordx16; LDS only holds the 8 KB cross-wave key reduce.
__global__ __launch_bounds__(512, 4) void vq_main(const float* __restrict__ x,
                                                  const float* __restrict__ cb,
                                                  const float* __restrict__ pk,
                                                  float* __restrict__ out) {
    __shared__ unsigned long long keys[NSPLIT * TOKS_PER_BLOCK];  // 8 KB
    __shared__ float lred[TPT];
    const int tid  = threadIdx.x;
    const int lane = tid & 63;
    const int s = __builtin_amdgcn_readfirstlane(tid >> 6);  // K-chunk id
    const int tbase = blockIdx.x * TOKS_PER_BLOCK;

    // this thread's 2 tokens (lane-contiguous 48B rows)
    float xs[TPT][DIM];
    float x2[TPT];
#pragma unroll
    for (int j = 0; j < TPT; ++j) {
        const float4* xp = (const float4*)(x + (size_t)(tbase + j * 64 + lane) * DIM);
        float4 a0 = xp[0], a1 = xp[1], a2 = xp[2];
        xs[j][0] = a0.x; xs[j][1] = a0.y; xs[j][2]  = a0.z; xs[j][3]  = a0.w;
        xs[j][4] = a1.x; xs[j][5] = a1.y; xs[j][6]  = a1.z; xs[j][7]  = a1.w;
        xs[j][8] = a2.x; xs[j][9] = a2.y; xs[j][10] = a2.z; xs[j][11] = a2.w;
        float t2 = 0.f;
#pragma unroll
        for (int d = 0; d < DIM; ++d) t2 = fmaf(xs[j][d], xs[j][d], t2);
        x2[j] = t2;
    }

    float best[TPT];
    int   bi[TPT];
#pragma unroll
    for (int j = 0; j < TPT; ++j) { best[j] = INFINITY; bi[j] = 0; }

    const int k0 = s * KCHUNK;
    // wave-uniform byte address of this wave's chunk (s is readfirstlane-uniform)
    unsigned long long cwa = (unsigned long long)(pk + (size_t)k0 * ROWF);

    // ---- 2-code double buffer, rows in SGPRs ----
    f32x16 A, B;
    asm volatile("s_load_dwordx16 %0, %1, 0" : "=s"(A) : "s"(cwa));
    asm volatile("s_waitcnt lgkmcnt(0)" : "+s"(A));
#pragma unroll
    for (int kk = 0; kk < KCHUNK; kk += 2) {
        // issue odd row kk+1 -> B (flies under A's 34-VALU compute window)
        asm volatile("s_load_dwordx16 %0, %1, 0"
                     : "=s"(B) : "s"(cwa + (unsigned long long)((kk + 1) * 64)));
        {   // score even code kk with A (A waited)
            const int k = k0 + kk;
#pragma unroll
            for (int j = 0; j < TPT; ++j) {
                float d = code_score_s(xs[j], x2[j], A);
                bool c = d < best[j];          // strict < => first occurrence
                best[j] = c ? d : best[j];
                bi[j]   = c ? k : bi[j];
            }
        }
        // exactly one SMEM op outstanding => lgkmcnt(0) waits B; "+s"(B) makes
        // B's consumers dataflow-ordered after this wait.
        asm volatile("s_waitcnt lgkmcnt(0)" : "+s"(B));
        // issue even row kk+2 -> A (last iter reads next chunk / zero pad row
        // 512 for s=7: in-bounds of pk[513], loaded but never scored)
        asm volatile("s_load_dwordx16 %0, %1, 0"
                     : "=s"(A) : "s"(cwa + (unsigned long long)((kk + 2) * 64)));
        {   // score odd code kk+1 with B
            const int k = k0 + kk + 1;
#pragma unroll
            for (int j = 0; j < TPT; ++j) {
                float d = code_score_s(xs[j], x2[j], B);
                bool c = d < best[j];
                best[j] = c ? d : best[j];
                bi[j]   = c ? k : bi[j];
            }
        }
        asm volatile("s_waitcnt lgkmcnt(0)" : "+s"(A));
    }

    // cross-wave argmin via u64 keys in LDS (global code ids 0..511)
#pragma unroll
    for (int j = 0; j < TPT; ++j)
        keys[s * TOKS_PER_BLOCK + j * 64 + lane] = mkkey(best[j], bi[j]);
    __syncthreads();

    // waves 0..1 finalize token group j==s (they hold xs[s] for those tokens)
    if (s < TPT) {
        const int tok = s * 64 + lane;
        unsigned long long m = keys[tok];
#pragma unroll
        for (int r = 1; r < NSPLIT; ++r) {
            unsigned long long v = keys[r * TOKS_PER_BLOCK + tok];
            m = v < m ? v : m;
        }
        const int bid = (int)(m & 0xffffffffULL);
        unsigned eu = (unsigned)(m >> 32);
        unsigned orig = (eu & 0x80000000u) ? (eu ^ 0x80000000u) : ~eu;
        const float bsc = __uint_as_float(orig);
        const int t = tbase + tok;

        float xv[DIM];
#pragma unroll
        for (int j = 0; j < TPT; ++j)
            if (j == s) {
#pragma unroll
                for (int d = 0; d < DIM; ++d) xv[d] = xs[j][d];
            }

        const float4* wrow = (const float4*)(cb + (size_t)bid * DIM);
        float4 q0 = wrow[0], q1 = wrow[1], q2 = wrow[2];
        float qs[DIM] = {q0.x, q0.y, q0.z, q0.w, q1.x, q1.y, q1.z, q1.w,
                         q2.x, q2.y, q2.z, q2.w};

        float4* qo = (float4*)(out + (size_t)t * DIM);
        float4 r0, r1, r2;
        r0.x = xv[0] + (qs[0] - xv[0]);    r0.y = xv[1] + (qs[1] - xv[1]);
        r0.z = xv[2] + (qs[2] - xv[2]);    r0.w = xv[3] + (qs[3] - xv[3]);
        r1.x = xv[4] + (qs[4] - xv[4]);    r1.y = xv[5] + (qs[5] - xv[5]);
        r1.z = xv[6] + (qs[6] - xv[6]);    r1.w = xv[7] + (qs[7] - xv[7]);
        r2.x = xv[8] + (qs[8] - xv[8]);    r2.y = xv[9] + (qs[9] - xv[9]);
        r2.z = xv[10] + (qs[10] - xv[10]); r2.w = xv[11] + (qs[11] - xv[11]);
        qo[0] = r0; qo[1] = r1; qo[2] = r2;

        out[QSIZE + t] = (float)bid;

        // loss partial: sum_d(q-x)^2 == best score (~1e-8 rel; thr ~2%).
        float ls = bsc * (1.25f / (float)QSIZE);
#pragma unroll
        for (int off = 32; off > 0; off >>= 1) ls += __shfl_down(ls, off);
        if (lane == 0) lred[s] = ls;
    }
    __syncthreads();
    // one fp32 atomic per block (accumulator zeroed by pack_cb; order
    // reassociation ~1e-7 rel, far under the ~2% loss threshold)
    if (tid == 0) atomicAdd(out + QSIZE + NTOK, lred[0] + lred[1]);
}
} // namespace

extern "C" void kernel_launch(void* const* d_in, const int* in_sizes, int n_in,
                              void* d_out, int out_size, void* d_ws, size_t ws_size,
                              hipStream_t stream) {
    const float* x  = (const float*)d_in[0];
    const float* cb = (const float*)d_in[1];
    float* out = (float*)d_out;
    float* pk  = (float*)d_ws;   // packed codebook: 513 x 16 floats = 32.8 KB

    pack_cb<<<2, 256, 0, stream>>>(cb, pk, out);
    vq_main<<<NBLK, 512, 0, stream>>>(x, cb, pk, out);
}

// Round 4
// 95.969 us; speedup vs baseline: 1.0647x; 1.0647x over previous
//
#include <hip/hip_runtime.h>
#include <math.h>

// VQ quantizer: x [512,256,12] fp32, codebook [512,12] fp32.
// Outputs (concat fp32): quantized_st [512*256*12], indices-as-float [512*256], loss [1].
//
// R11: R7 (LDS path) and R10 (SGPR s_load path) both plateaued at ~46us =
// 3x the ~15us VALU issue floor, VALUBusy ~40%. Common cause: a per-code
// memory round-trip through a shared low-throughput port (R7: LDS pipe,
// 4 ds_reads/code/wave = ~672 LDS-cy/CU/code-round > 544 VALU-cy; R10:
// scalar K$ streaming, queueing ~1700 cy/code). Occupancy can't hide a
// saturated pipe. Fix: NO memory in the inner loop. The wave's 64-code
// chunk lives lane-sharded in 13 VGPRs (lane l = code s*64+l: w[0..11],w2);
// per code, 13 v_readlane broadcasts (register-file op, VALU pipe, zero
// latency/wait) + TPT=4 x 17 VALU of scoring. 0.32 instr/pair -> ~17us floor.
// w2 computed in-lane with the EXACT pack_cb fmaf chain => pack_cb deleted;
// a 1-block init zeroes the loss slot (stream-ordered before atomics).
namespace {
constexpr int KCB   = 512;
constexpr int DIM   = 12;
constexpr int NTOK  = 512 * 256;       // 131072
constexpr int QSIZE = NTOK * DIM;      // 1572864
constexpr int NSPLIT = 8;              // waves per block == K chunks
constexpr int KCHUNK = KCB / NSPLIT;   // 64 codes per wave == 64 lanes
constexpr int TPT    = 4;              // tokens/thread (amortizes broadcasts)
constexpr int TOKS_PER_BLOCK = 64 * TPT;        // 256
constexpr int NBLK   = NTOK / TOKS_PER_BLOCK;   // 512 blocks x 512 thr

// u64 (monotone(score), k) unsigned-min == exact lexicographic
// first-occurrence argmin (validated R2-R10).
__device__ inline unsigned long long mkkey(float v, int k) {
    unsigned su = __float_as_uint(v);
    su = (su & 0x80000000u) ? ~su : (su | 0x80000000u);
    return ((unsigned long long)su << 32) | (unsigned)k;
}

__device__ inline float bcast(float v, int lane) {
    return __uint_as_float(__builtin_amdgcn_readlane(__float_as_uint(v), lane));
}

// zero the loss accumulator (stream-ordered before vq_main's atomics;
// re-runs every replay after harness re-poisoning).
__global__ void init_loss(float* __restrict__ out) {
    if (threadIdx.x == 0) out[QSIZE + NTOK] = 0.f;
}

// Block = 256 tokens x 8 K-splits. Codebook chunk lane-sharded in VGPRs;
// inner loop touches NO memory. LDS only for the 16 KB cross-wave key reduce.
__global__ __launch_bounds__(512, 4) void vq_main(const float* __restrict__ x,
                                                  const float* __restrict__ cb,
                                                  float* __restrict__ out) {
    __shared__ unsigned long long keys[NSPLIT * TOKS_PER_BLOCK];  // 16 KB
    __shared__ float lred[TPT];
    const int tid  = threadIdx.x;
    const int lane = tid & 63;
    const int s = __builtin_amdgcn_readfirstlane(tid >> 6);  // K-chunk id
    const int tbase = blockIdx.x * TOKS_PER_BLOCK;

    // lane's code: kc = s*64 + lane. Row -> 13 VGPRs; w2 via the EXACT
    // fmaf chain previously in pack_cb (bit-identical per code).
    float cw[13];
    {
        const int kc = (s << 6) + lane;
        const float4* wp = (const float4*)(cb + (size_t)kc * DIM);
        float4 c0 = wp[0], c1 = wp[1], c2 = wp[2];
        cw[0] = c0.x; cw[1] = c0.y; cw[2]  = c0.z; cw[3]  = c0.w;
        cw[4] = c1.x; cw[5] = c1.y; cw[6]  = c1.z; cw[7]  = c1.w;
        cw[8] = c2.x; cw[9] = c2.y; cw[10] = c2.z; cw[11] = c2.w;
        float w2 = 0.f;
#pragma unroll
        for (int d = 0; d < DIM; ++d) w2 = fmaf(cw[d], cw[d], w2);
        cw[12] = w2;
    }

    // this thread's 4 tokens (lane-contiguous 48B rows)
    float xs[TPT][DIM];
    float x2[TPT];
#pragma unroll
    for (int j = 0; j < TPT; ++j) {
        const float4* xp = (const float4*)(x + (size_t)(tbase + j * 64 + lane) * DIM);
        float4 a0 = xp[0], a1 = xp[1], a2 = xp[2];
        xs[j][0] = a0.x; xs[j][1] = a0.y; xs[j][2]  = a0.z; xs[j][3]  = a0.w;
        xs[j][4] = a1.x; xs[j][5] = a1.y; xs[j][6]  = a1.z; xs[j][7]  = a1.w;
        xs[j][8] = a2.x; xs[j][9] = a2.y; xs[j][10] = a2.z; xs[j][11] = a2.w;
        float t2 = 0.f;
#pragma unroll
        for (int d = 0; d < DIM; ++d) t2 = fmaf(xs[j][d], xs[j][d], t2);
        x2[j] = t2;
    }

    float best[TPT];
    int   bi[TPT];
#pragma unroll
    for (int j = 0; j < TPT; ++j) { best[j] = INFINITY; bi[j] = 0; }

    const int k0 = s << 6;   // global code id of chunk start

    // ---- inner loop: pure registers. kk ascending => strict < keeps the
    // first occurrence in global-k order (EXACT semantics of R1-R10).
    // unroll 8: ~650-instr body (I$-friendly); readlane lane = SGPR-uniform.
#pragma unroll 8
    for (int kk = 0; kk < KCHUNK; ++kk) {
        float w[13];
#pragma unroll
        for (int d = 0; d < 13; ++d) w[d] = bcast(cw[d], kk);
        const int k = k0 + kk;
#pragma unroll
        for (int j = 0; j < TPT; ++j) {
            // EXACT score sequence validated R1-R10. Do not reorder.
            float xw = 0.f;
            xw = fmaf(xs[j][0],  w[0],  xw);
            xw = fmaf(xs[j][1],  w[1],  xw);
            xw = fmaf(xs[j][2],  w[2],  xw);
            xw = fmaf(xs[j][3],  w[3],  xw);
            xw = fmaf(xs[j][4],  w[4],  xw);
            xw = fmaf(xs[j][5],  w[5],  xw);
            xw = fmaf(xs[j][6],  w[6],  xw);
            xw = fmaf(xs[j][7],  w[7],  xw);
            xw = fmaf(xs[j][8],  w[8],  xw);
            xw = fmaf(xs[j][9],  w[9],  xw);
            xw = fmaf(xs[j][10], w[10], xw);
            xw = fmaf(xs[j][11], w[11], xw);
            float d = fmaf(-2.f, xw, x2[j]) + w[12];
            bool c = d < best[j];          // strict < => first occurrence
            best[j] = c ? d : best[j];
            bi[j]   = c ? k : bi[j];
        }
    }

    // cross-wave argmin via u64 keys in LDS (global code ids 0..511)
#pragma unroll
    for (int j = 0; j < TPT; ++j)
        keys[s * TOKS_PER_BLOCK + j * 64 + lane] = mkkey(best[j], bi[j]);
    __syncthreads();

    // waves 0..3 finalize token group j==s (they hold xs[s] for those tokens)
    if (s < TPT) {
        const int tok = s * 64 + lane;
        unsigned long long m = keys[tok];
#pragma unroll
        for (int r = 1; r < NSPLIT; ++r) {
            unsigned long long v = keys[r * TOKS_PER_BLOCK + tok];
            m = v < m ? v : m;
        }
        const int bid = (int)(m & 0xffffffffULL);
        unsigned eu = (unsigned)(m >> 32);
        unsigned orig = (eu & 0x80000000u) ? (eu ^ 0x80000000u) : ~eu;
        const float bsc = __uint_as_float(orig);
        const int t = tbase + tok;

        float xv[DIM];
#pragma unroll
        for (int j = 0; j < TPT; ++j)
            if (j == s) {
#pragma unroll
                for (int d = 0; d < DIM; ++d) xv[d] = xs[j][d];
            }

        const float4* wrow = (const float4*)(cb + (size_t)bid * DIM);
        float4 q0 = wrow[0], q1 = wrow[1], q2 = wrow[2];
        float qs[DIM] = {q0.x, q0.y, q0.z, q0.w, q1.x, q1.y, q1.z, q1.w,
                         q2.x, q2.y, q2.z, q2.w};

        float4* qo = (float4*)(out + (size_t)t * DIM);
        float4 r0, r1, r2;
        r0.x = xv[0] + (qs[0] - xv[0]);    r0.y = xv[1] + (qs[1] - xv[1]);
        r0.z = xv[2] + (qs[2] - xv[2]);    r0.w = xv[3] + (qs[3] - xv[3]);
        r1.x = xv[4] + (qs[4] - xv[4]);    r1.y = xv[5] + (qs[5] - xv[5]);
        r1.z = xv[6] + (qs[6] - xv[6]);    r1.w = xv[7] + (qs[7] - xv[7]);
        r2.x = xv[8] + (qs[8] - xv[8]);    r2.y = xv[9] + (qs[9] - xv[9]);
        r2.z = xv[10] + (qs[10] - xv[10]); r2.w = xv[11] + (qs[11] - xv[11]);
        qo[0] = r0; qo[1] = r1; qo[2] = r2;

        out[QSIZE + t] = (float)bid;

        // loss partial: sum_d(q-x)^2 == best score (~1e-8 rel; thr ~2%).
        float ls = bsc * (1.25f / (float)QSIZE);
#pragma unroll
        for (int off = 32; off > 0; off >>= 1) ls += __shfl_down(ls, off);
        if (lane == 0) lred[s] = ls;
    }
    __syncthreads();
    // one fp32 atomic per block (accumulator zeroed by init_loss; order
    // reassociation ~1e-7 rel, far under the ~2% loss threshold)
    if (tid == 0) atomicAdd(out + QSIZE + NTOK, lred[0] + lred[1] + lred[2] + lred[3]);
}
} // namespace

extern "C" void kernel_launch(void* const* d_in, const int* in_sizes, int n_in,
                              void* d_out, int out_size, void* d_ws, size_t ws_size,
                              hipStream_t stream) {
    const float* x  = (const float*)d_in[0];
    const float* cb = (const float*)d_in[1];
    float* out = (float*)d_out;
    (void)d_ws; (void)ws_size;

    init_loss<<<1, 64, 0, stream>>>(out);
    vq_main<<<NBLK, 512, 0, stream>>>(x, cb, out);
}